// Round 1
// 355.525 us; speedup vs baseline: 1.0532x; 1.0532x over previous
//
#include <hip/hip_runtime.h>
#include <math.h>

// Problem constants: B=4, M=8192, D=512, N=128, P=1
#define B_ 4
#define M_ 8192
#define D_ 512
#define N_ 128
#define TOK (B_ * M_)    // 32768
#define MC_ 32           // split-K chunks over M for xs
#define MLEN (M_ / MC_)  // 256 rows per chunk

// Workspace layout (float offsets)
#define OFF_CS 0                                   // [512] colsum of raw exp
#define OFF_XS (OFF_CS + 512)                      // [B*N*D] normalized slot inputs fp32
#define OFF_PBT (OFF_XS + B_ * N_ * D_)            // [N*D] bf16 phi^T (shorts)
#define OFF_E (OFF_PBT + N_ * D_ / 2)              // [TOK*N] raw exp(logits) fp32
#define OFF_EWT (OFF_E + (size_t)TOK * N_)         // [N][TOK] bf16 exp^T (shorts)
#define OFF_XB (OFF_EWT + (size_t)N_ * TOK / 2)    // [TOK][D] bf16 xn (shorts)
#define OFF_XBT (OFF_XB + (size_t)TOK * D_ / 2)    // [D][TOK] bf16 xn^T (shorts)
#define OFF_YST (OFF_XBT + (size_t)D_ * TOK / 2)   // [B*D*N] bf16 ys^T (shorts)
#define OFF_XP (OFF_YST + B_ * D_ * N_ / 2)        // [MC*B*N*D] fp32 partials

typedef __attribute__((ext_vector_type(8))) short s16x8;
typedef __attribute__((ext_vector_type(4))) float f32x4;

__device__ inline short f2bf(float f) {  // RNE round to bf16
    union { float f; unsigned u; } v;
    v.f = f;
    unsigned r = v.u + 0x7fffu + ((v.u >> 16) & 1u);
    return (short)(r >> 16);
}

// ---------------------------------------------------------------------------
// K0: phi col-normalize -> pbt[n][d] bf16 = scale * phi[d][n]/max(||phi[:,n]||,eps)
__global__ __launch_bounds__(128) void k_phinorm(const float* __restrict__ phi,
                                                 const float* __restrict__ scale,
                                                 short* __restrict__ pbt) {
    __shared__ float sred[128];
    int n = blockIdx.x, tid = threadIdx.x;
    float ss = 0.f;
    for (int d = tid; d < D_; d += 128) {
        float v = phi[d * N_ + n];
        ss += v * v;
    }
    sred[tid] = ss;
    __syncthreads();
    for (int s = 64; s > 0; s >>= 1) {
        if (tid < s) sred[tid] += sred[tid + s];
        __syncthreads();
    }
    float sc = scale[0] / fmaxf(sqrtf(sred[0]), 1e-12f);
    for (int d = tid; d < D_; d += 128) pbt[n * D_ + d] = f2bf(phi[d * N_ + n] * sc);
}

// ---------------------------------------------------------------------------
// K1: token normalize. Per block: 32 rows. Computes rn in-block, writes
// xb[m][d] = bf16(x*rn) (row-major) and xbt[d][m] (transposed, via LDS with
// an additive 8-granular skew to keep the b16 scatter ~conflict-free).
__global__ __launch_bounds__(256) void k_prep(const float* __restrict__ x,
                                              short* __restrict__ xb,
                                              short* __restrict__ xbt) {
    __shared__ short T[512 * 40];  // [d][slot], stride 40 shorts (80B, 16B-aligned rows)
    __shared__ float sred[32][8];
    __shared__ float srn[32];
    int t = threadIdx.x;
    int m0 = blockIdx.x * 32;
    int row = t >> 3, o8 = t & 7;  // 8 threads per row, 64 d each
    const float4* xr = (const float4*)&x[(size_t)(m0 + row) * D_ + o8 * 64];
    float4 v[16];
    float ss = 0.f;
#pragma unroll
    for (int i = 0; i < 16; i++) {
        v[i] = xr[i];
        ss += v[i].x * v[i].x + v[i].y * v[i].y + v[i].z * v[i].z + v[i].w * v[i].w;
    }
    sred[row][o8] = ss;
    __syncthreads();
    if (t < 32) {
        float s = sred[t][0] + sred[t][1] + sred[t][2] + sred[t][3] +
                  sred[t][4] + sred[t][5] + sred[t][6] + sred[t][7];
        srn[t] = 1.0f / fmaxf(sqrtf(s), 1e-12f);
    }
    __syncthreads();
    float rv = srn[row];
    short* xrow = &xb[(size_t)(m0 + row) * D_ + o8 * 64];
    // skew: slot = (m~ + 8*((d>>6)&3)) & 31 ; here d>>6 == o8
    int slot = (row + 8 * (o8 & 3)) & 31;
    int dbase = o8 * 64;
#pragma unroll
    for (int i = 0; i < 16; i++) {
        short4 w = {f2bf(v[i].x * rv), f2bf(v[i].y * rv), f2bf(v[i].z * rv), f2bf(v[i].w * rv)};
        *(short4*)&xrow[i * 4] = w;
        int d = dbase + i * 4;
        T[(d + 0) * 40 + slot] = w.x;
        T[(d + 1) * 40 + slot] = w.y;
        T[(d + 2) * 40 + slot] = w.z;
        T[(d + 3) * 40 + slot] = w.w;
    }
    __syncthreads();
    // write out xbt[d][m0..m0+31]: un-skew by reading shifted 8-groups
#pragma unroll
    for (int p = 0; p < 8; p++) {
        int d = p * 64 + (t >> 2);
        int g = t & 3;
        int sgrp = (g + ((d >> 6) & 3)) & 3;
        s16x8 val = *(const s16x8*)&T[d * 40 + sgrp * 8];
        *(s16x8*)&xbt[(size_t)d * TOK + m0 + g * 8] = val;
    }
}

// ---------------------------------------------------------------------------
// K2: logits via bf16 MFMA. Block: 128m x 128n, 512 thr (8 waves, 4x2).
// Writes E[m][n] = exp(logit) fp32 (combine path, unchanged numerics),
// colsum atomics, and ewt[n][m] bf16 (for the MFMA dispatch GEMM) via an
// LDS transpose that reuses the dead As/Bs buffers in two n-halves.
__global__ __launch_bounds__(512) void k_logits(const short* __restrict__ xb,
                                                const short* __restrict__ pbt,
                                                float* __restrict__ E,
                                                short* __restrict__ ewt,
                                                float* __restrict__ colsum) {
    __shared__ short smem[2 * 128 * 40];  // As | Bs ; reused as T[64][136] after loop
    short* As = smem;
    short* Bs = smem + 128 * 40;
    int t = threadIdx.x;
    int r0 = blockIdx.x * 128;
    int sm = t >> 2;           // staging row (m for A, n for B)
    int kq = (t & 3) * 8;      // k sub-chunk
    const short* xrow = &xb[(size_t)(r0 + sm) * D_ + kq];
    const short* brow = &pbt[sm * D_ + kq];
    int wid = t >> 6, lane = t & 63;
    int quad = lane >> 4, l15 = lane & 15;
    int mw = (wid >> 1) * 32, nw = (wid & 1) * 64;
    f32x4 acc[2][4] = {};

    for (int k0 = 0; k0 < D_; k0 += 32) {
        s16x8 av = *(const s16x8*)&xrow[k0];
        s16x8 bv = *(const s16x8*)&brow[k0];
        *(s16x8*)&As[sm * 40 + kq] = av;
        *(s16x8*)&Bs[sm * 40 + kq] = bv;
        __syncthreads();
        s16x8 af[2], bf[4];
#pragma unroll
        for (int i = 0; i < 2; i++)
            af[i] = *(const s16x8*)&As[(mw + i * 16 + l15) * 40 + quad * 8];
#pragma unroll
        for (int j = 0; j < 4; j++)
            bf[j] = *(const s16x8*)&Bs[(nw + j * 16 + l15) * 40 + quad * 8];
#pragma unroll
        for (int i = 0; i < 2; i++)
#pragma unroll
            for (int j = 0; j < 4; j++)
                acc[i][j] = __builtin_amdgcn_mfma_f32_16x16x32_bf16(af[i], bf[j], acc[i][j], 0, 0, 0);
        __syncthreads();
    }
    int bb = r0 >> 13;
    short4 ebf[2][4];
#pragma unroll
    for (int j = 0; j < 4; j++) {
        int n = nw + j * 16 + l15;
        float cs = 0.f;
#pragma unroll
        for (int i = 0; i < 2; i++) {
            int mb = r0 + mw + i * 16 + quad * 4;
            f32x4 vv = acc[i][j];
            float e0 = __expf(vv[0]), e1 = __expf(vv[1]), e2 = __expf(vv[2]), e3 = __expf(vv[3]);
            cs += e0 + e1 + e2 + e3;
            E[(size_t)(mb + 0) * N_ + n] = e0;
            E[(size_t)(mb + 1) * N_ + n] = e1;
            E[(size_t)(mb + 2) * N_ + n] = e2;
            E[(size_t)(mb + 3) * N_ + n] = e3;
            short4 eb = {f2bf(e0), f2bf(e1), f2bf(e2), f2bf(e3)};
            ebf[i][j] = eb;
        }
        cs += __shfl_xor(cs, 16, 64);
        cs += __shfl_xor(cs, 32, 64);
        if (lane < 16) atomicAdd(&colsum[bb * N_ + n], cs);
    }
    // ewt[n][r0..r0+127] bf16 via LDS transpose, two 64-row n-halves
    short* T = smem;  // 64 x 136 shorts (fits in As+Bs region)
#pragma unroll
    for (int h = 0; h < 2; h++) {
        if ((wid & 1) == h) {
#pragma unroll
            for (int i = 0; i < 2; i++) {
                int mb = mw + i * 16 + quad * 4;  // local m 0..127
#pragma unroll
                for (int j = 0; j < 4; j++) {
                    int nl = j * 16 + l15;       // local n within half 0..63
                    *(short4*)&T[nl * 136 + mb] = ebf[i][j];
                }
            }
        }
        __syncthreads();
        {
            int nl = t >> 3, c = t & 7;
            s16x8 v0 = *(const s16x8*)&T[nl * 136 + c * 16];
            s16x8 v1 = *(const s16x8*)&T[nl * 136 + c * 16 + 8];
            size_t go = (size_t)(h * 64 + nl) * TOK + r0 + c * 16;
            *(s16x8*)&ewt[go] = v0;
            *(s16x8*)&ewt[go + 8] = v1;
        }
        __syncthreads();
    }
}

// ---------------------------------------------------------------------------
// K3: xs partials via bf16 MFMA. part[mc][b][n][d] = sum_m ewt[n][m]*xbt[d][m].
// Grid b(4) x mc(32) x dt(4) = 512 blocks, 256 thr (4 waves, 2n x 2d),
// tile 128n x 128d, K = 256 m per block.
__global__ __launch_bounds__(256) void k_xs(const short* __restrict__ ewt,
                                            const short* __restrict__ xbt,
                                            float* __restrict__ part) {
    __shared__ short An[128 * 40];  // [n][k-chunk 0..31]
    __shared__ short Bd[128 * 40];  // [d][k-chunk 0..31]
    int t = threadIdx.x, bi = blockIdx.x;
    int dt = bi & 3, mc = (bi >> 2) & 31, b = bi >> 7;
    int d0 = dt * 128;
    size_t mbase = (size_t)b * M_ + (size_t)mc * MLEN;
    int srow = t >> 1, shalf = (t & 1) * 16;
    const short* arow = &ewt[(size_t)srow * TOK + mbase + shalf];
    const short* brow = &xbt[(size_t)(d0 + srow) * TOK + mbase + shalf];
    int wid = t >> 6, lane = t & 63;
    int quad = lane >> 4, l15 = lane & 15;
    int nw = (wid >> 1) * 64, dw = (wid & 1) * 64;
    f32x4 acc[4][4] = {};

    for (int k0 = 0; k0 < MLEN; k0 += 32) {
        s16x8 a0 = *(const s16x8*)&arow[k0];
        s16x8 a1 = *(const s16x8*)&arow[k0 + 8];
        s16x8 b0 = *(const s16x8*)&brow[k0];
        s16x8 b1 = *(const s16x8*)&brow[k0 + 8];
        *(s16x8*)&An[srow * 40 + shalf] = a0;
        *(s16x8*)&An[srow * 40 + shalf + 8] = a1;
        *(s16x8*)&Bd[srow * 40 + shalf] = b0;
        *(s16x8*)&Bd[srow * 40 + shalf + 8] = b1;
        __syncthreads();
        s16x8 af[4], bf[4];
#pragma unroll
        for (int i = 0; i < 4; i++)
            af[i] = *(const s16x8*)&An[(nw + i * 16 + l15) * 40 + quad * 8];
#pragma unroll
        for (int j = 0; j < 4; j++)
            bf[j] = *(const s16x8*)&Bd[(dw + j * 16 + l15) * 40 + quad * 8];
#pragma unroll
        for (int i = 0; i < 4; i++)
#pragma unroll
            for (int j = 0; j < 4; j++)
                acc[i][j] = __builtin_amdgcn_mfma_f32_16x16x32_bf16(af[i], bf[j], acc[i][j], 0, 0, 0);
        __syncthreads();
    }
    size_t pbase = (((size_t)mc * B_ + b) * N_) * D_ + d0;
#pragma unroll
    for (int i = 0; i < 4; i++) {
        int nb = nw + i * 16 + quad * 4;
#pragma unroll
        for (int j = 0; j < 4; j++) {
            int d = dw + j * 16 + l15;
            f32x4 vv = acc[i][j];
            part[pbase + (size_t)(nb + 0) * D_ + d] = vv[0];
            part[pbase + (size_t)(nb + 1) * D_ + d] = vv[1];
            part[pbase + (size_t)(nb + 2) * D_ + d] = vv[2];
            part[pbase + (size_t)(nb + 3) * D_ + d] = vv[3];
        }
    }
}

// ---------------------------------------------------------------------------
// K3b: reduce partials over mc, normalize by colsum -> xs[b][n][d] fp32
__global__ __launch_bounds__(256) void k_xsum(const float* __restrict__ part,
                                              const float* __restrict__ colsum,
                                              float* __restrict__ xs) {
    int bi = blockIdx.x;  // b*N + n
    int tid = threadIdx.x;
    float inv = 1.0f / colsum[bi];
    size_t base = (size_t)bi * D_ + tid * 2;
    float sx = 0.f, sy = 0.f;
#pragma unroll 8
    for (int mc = 0; mc < MC_; mc++) {
        float2 v = *(const float2*)&part[(size_t)mc * (B_ * N_ * D_) + base];
        sx += v.x;
        sy += v.y;
    }
    float2 o = {sx * inv, sy * inv};
    *(float2*)&xs[base] = o;
}

// ---------------------------------------------------------------------------
// K4: per-expert linear (HBM-bound on W), bias add, fused bf16 transpose
// store ysT[b][e][n]. Grid n(128) x eq(4).
__global__ __launch_bounds__(256) void k_ys(const float* __restrict__ xs,
                                            const float* __restrict__ W,
                                            const float* __restrict__ bias,
                                            short* __restrict__ ysT) {
    __shared__ float xsn[B_][D_];
    int bi = blockIdx.x;
    int n = bi >> 2, eq = bi & 3;
    int tid = threadIdx.x;
    {
        int lb = tid >> 6, ld = (tid & 63) * 4;
        *(float4*)&xsn[lb][ld] = *(const float4*)&xs[((size_t)lb * N_ + n) * D_ + ld];
        *(float4*)&xsn[lb][256 + ld] =
            *(const float4*)&xs[((size_t)lb * N_ + n) * D_ + 256 + ld];
    }
    __syncthreads();
    int b = tid >> 6;
    int e = eq * 128 + (tid & 63) * 2;
    const float* Wn = W + (size_t)n * D_ * D_ + e;
    float a0 = 0.f, a1 = 0.f;
#pragma unroll 8
    for (int d = 0; d < D_; d++) {
        float2 w = *(const float2*)&Wn[(size_t)d * D_];
        float xv = xsn[b][d];
        a0 += xv * w.x;
        a1 += xv * w.y;
    }
    float2 bv = *(const float2*)&bias[n * D_ + e];
    ysT[((size_t)b * D_ + e) * N_ + n] = f2bf(a0 + bv.x);
    ysT[((size_t)b * D_ + e + 1) * N_ + n] = f2bf(a1 + bv.y);
}

// ---------------------------------------------------------------------------
// K5: combine via bf16 MFMA. Block: 128m x 128d, K=n=128 in 4 chunks of 32.
// y[m][d] = sum_n (E[m][n]/rowsum[m]) * ysT[d][n]; rowsum in fp32 from staging.
__global__ __launch_bounds__(256) void k_combine(const float* __restrict__ E,
                                                 const short* __restrict__ ysT,
                                                 float* __restrict__ y) {
    __shared__ short As[128 * 40];  // [m][n-chunk 0..31]
    __shared__ short Bs[128 * 40];  // [d][n-chunk 0..31]
    __shared__ float rsA[2][128];
    __shared__ float rsinv[128];
    int t = threadIdx.x, bi = blockIdx.x;
    int dt = bi & 3, mt = bi >> 2;
    int r0 = mt * 128, d0 = dt * 128;
    int bb = r0 >> 13;
    int sm = t >> 1, nh = (t & 1) * 16;
    const float* erow = &E[(size_t)(r0 + sm) * N_ + nh];
    const short* yrow = &ysT[((size_t)bb * D_ + d0 + sm) * N_ + nh];
    int wid = t >> 6, lane = t & 63;
    int quad = lane >> 4, l15 = lane & 15;
    int mw = (wid >> 1) * 64, dw = (wid & 1) * 64;
    f32x4 acc[4][4] = {};
    float rsp = 0.f;

    for (int ks = 0; ks < 4; ks++) {
        int n0 = ks * 32;
        float4 e0 = *(const float4*)&erow[n0];
        float4 e1 = *(const float4*)&erow[n0 + 4];
        float4 e2 = *(const float4*)&erow[n0 + 8];
        float4 e3 = *(const float4*)&erow[n0 + 12];
        rsp += e0.x + e0.y + e0.z + e0.w + e1.x + e1.y + e1.z + e1.w +
               e2.x + e2.y + e2.z + e2.w + e3.x + e3.y + e3.z + e3.w;
        short4 w0 = {f2bf(e0.x), f2bf(e0.y), f2bf(e0.z), f2bf(e0.w)};
        short4 w1 = {f2bf(e1.x), f2bf(e1.y), f2bf(e1.z), f2bf(e1.w)};
        short4 w2 = {f2bf(e2.x), f2bf(e2.y), f2bf(e2.z), f2bf(e2.w)};
        short4 w3 = {f2bf(e3.x), f2bf(e3.y), f2bf(e3.z), f2bf(e3.w)};
        *(short4*)&As[sm * 40 + nh + 0] = w0;
        *(short4*)&As[sm * 40 + nh + 4] = w1;
        *(short4*)&As[sm * 40 + nh + 8] = w2;
        *(short4*)&As[sm * 40 + nh + 12] = w3;
        *(s16x8*)&Bs[sm * 40 + nh] = *(const s16x8*)&yrow[n0];
        *(s16x8*)&Bs[sm * 40 + nh + 8] = *(const s16x8*)&yrow[n0 + 8];
        __syncthreads();
        s16x8 af[4], bf[4];
#pragma unroll
        for (int i = 0; i < 4; i++)
            af[i] = *(const s16x8*)&As[(mw + i * 16 + l15) * 40 + quad * 8];
#pragma unroll
        for (int j = 0; j < 4; j++)
            bf[j] = *(const s16x8*)&Bs[(dw + j * 16 + l15) * 40 + quad * 8];
#pragma unroll
        for (int i = 0; i < 4; i++)
#pragma unroll
            for (int j = 0; j < 4; j++)
                acc[i][j] = __builtin_amdgcn_mfma_f32_16x16x32_bf16(af[i], bf[j], acc[i][j], 0, 0, 0);
        __syncthreads();
    }
    rsA[t & 1][sm] = rsp;
    __syncthreads();
    if (t < 128) rsinv[t] = 1.0f / (rsA[0][t] + rsA[1][t]);
    __syncthreads();
#pragma unroll
    for (int i = 0; i < 4; i++) {
        int mb = mw + i * 16 + quad * 4;
        float i0 = rsinv[mb], i1 = rsinv[mb + 1], i2 = rsinv[mb + 2], i3 = rsinv[mb + 3];
#pragma unroll
        for (int j = 0; j < 4; j++) {
            int d = d0 + dw + j * 16 + l15;
            f32x4 v = acc[i][j];
            y[(size_t)(r0 + mb + 0) * D_ + d] = v[0] * i0;
            y[(size_t)(r0 + mb + 1) * D_ + d] = v[1] * i1;
            y[(size_t)(r0 + mb + 2) * D_ + d] = v[2] * i2;
            y[(size_t)(r0 + mb + 3) * D_ + d] = v[3] * i3;
        }
    }
}

// ---------------------------------------------------------------------------
extern "C" void kernel_launch(void* const* d_in, const int* in_sizes, int n_in,
                              void* d_out, int out_size, void* d_ws, size_t ws_size,
                              hipStream_t stream) {
    const float* x = (const float*)d_in[0];
    const float* phi = (const float*)d_in[1];
    const float* scale = (const float*)d_in[2];
    const float* W = (const float*)d_in[3];
    const float* bias = (const float*)d_in[4];
    float* y = (float*)d_out;
    float* ws = (float*)d_ws;

    float* colsum = ws + OFF_CS;
    float* xs = ws + OFF_XS;
    short* pbt = (short*)(ws + OFF_PBT);
    float* E = ws + OFF_E;
    short* ewt = (short*)(ws + OFF_EWT);
    short* xb = (short*)(ws + OFF_XB);
    short* xbt = (short*)(ws + OFF_XBT);
    short* ysT = (short*)(ws + OFF_YST);
    float* part = ws + OFF_XP;

    hipMemsetAsync(colsum, 0, 512 * sizeof(float), stream);

    k_phinorm<<<N_, 128, 0, stream>>>(phi, scale, pbt);
    k_prep<<<TOK / 32, 256, 0, stream>>>(x, xb, xbt);
    k_logits<<<TOK / 128, 512, 0, stream>>>(xb, pbt, E, ewt, colsum);
    k_xs<<<B_ * MC_ * 4, 256, 0, stream>>>(ewt, xbt, part);
    k_xsum<<<B_ * N_, 256, 0, stream>>>(part, colsum, xs);
    k_ys<<<N_ * 4, 256, 0, stream>>>(xs, W, bias, ysT);
    k_combine<<<(TOK / 128) * 4, 256, 0, stream>>>(E, ysT, y);
}

// Round 2
// 327.069 us; speedup vs baseline: 1.1449x; 1.0870x over previous
//
#include <hip/hip_runtime.h>
#include <math.h>

// Problem constants: B=4, M=8192, D=512, N=128, P=1
#define B_ 4
#define M_ 8192
#define D_ 512
#define N_ 128
#define TOK (B_ * M_)    // 32768
#define MC_ 16           // split-K chunks over M for xs
#define MLEN (M_ / MC_)  // 512 rows per chunk

// Workspace layout (float offsets)
#define OFF_CS 0                                   // [512] colsum of raw exp
#define OFF_XS (OFF_CS + 512)                      // [B*N*D] normalized slot inputs fp32
#define OFF_PBT (OFF_XS + B_ * N_ * D_)            // [N*D] bf16 phi^T (shorts)
#define OFF_E (OFF_PBT + N_ * D_ / 2)              // [TOK*N] raw exp(logits) fp32
#define OFF_EWT (OFF_E + (size_t)TOK * N_)         // [N][TOK] bf16 (E*rn)^T (shorts)
#define OFF_XBT (OFF_EWT + (size_t)N_ * TOK / 2)   // [D][TOK] bf16 raw-x^T (shorts)
#define OFF_YST (OFF_XBT + (size_t)D_ * TOK / 2)   // [B*D*N] bf16 ys^T (shorts)
#define OFF_XP (OFF_YST + B_ * D_ * N_ / 2)        // [MC*B*N*D] fp32 partials

typedef __attribute__((ext_vector_type(8))) short s16x8;
typedef __attribute__((ext_vector_type(4))) float f32x4;

__device__ inline short f2bf(float f) {  // RNE round to bf16
    union { float f; unsigned u; } v;
    v.f = f;
    unsigned r = v.u + 0x7fffu + ((v.u >> 16) & 1u);
    return (short)(r >> 16);
}

// ---------------------------------------------------------------------------
// K0: phi col-normalize -> pbt[n][d] bf16 = scale * phi[d][n]/max(||phi[:,n]||,eps)
__global__ __launch_bounds__(128) void k_phinorm(const float* __restrict__ phi,
                                                 const float* __restrict__ scale,
                                                 short* __restrict__ pbt) {
    __shared__ float sred[128];
    int n = blockIdx.x, tid = threadIdx.x;
    float ss = 0.f;
    for (int d = tid; d < D_; d += 128) {
        float v = phi[d * N_ + n];
        ss += v * v;
    }
    sred[tid] = ss;
    __syncthreads();
    for (int s = 64; s > 0; s >>= 1) {
        if (tid < s) sred[tid] += sred[tid + s];
        __syncthreads();
    }
    float sc = scale[0] / fmaxf(sqrtf(sred[0]), 1e-12f);
    for (int d = tid; d < D_; d += 128) pbt[n * D_ + d] = f2bf(phi[d * N_ + n] * sc);
}

// ---------------------------------------------------------------------------
// K1: logits mega-kernel. Reads fp32 x directly, MFMAs on RAW bf16(x)
// (logit = rn[m] * rawdot, rn applied in epilogue). Per k-step also
// transpose-writes the As staging tile to xbt[d][m] (raw-x bf16, m-contig)
// for the dispatch GEMM. Emits E fp32, ewt = bf16(E*rn) transposed, colsum.
__global__ __launch_bounds__(512) void k_logits(const float* __restrict__ x,
                                                const short* __restrict__ pbt,
                                                float* __restrict__ E,
                                                short* __restrict__ ewt,
                                                short* __restrict__ xbt,
                                                float* __restrict__ colsum) {
    __shared__ short smem[2 * 128 * 40];  // As | Bs ; reused as T[64][136] after loop
    __shared__ float rnS[128];
    short* As = smem;
    short* Bs = smem + 128 * 40;
    int t = threadIdx.x;
    int r0 = blockIdx.x * 128;
    int sm = t >> 2;           // staging row (m for A, n for B)
    int kq = (t & 3) * 8;      // k sub-chunk
    const float* xrow = &x[(size_t)(r0 + sm) * D_ + kq];
    const short* brow = &pbt[sm * D_ + kq];
    int wid = t >> 6, lane = t & 63;
    int quad = lane >> 4, l15 = lane & 15;
    int mw = (wid >> 1) * 32, nw = (wid & 1) * 64;
    int dl = t & 31, mg = t >> 5;  // xbt transpose mapping: 32 d x 16 m-groups
    f32x4 acc[2][4] = {};
    float ss = 0.f;

    for (int k0 = 0; k0 < D_; k0 += 32) {
        float4 a0 = *(const float4*)&xrow[k0];
        float4 a1 = *(const float4*)&xrow[k0 + 4];
        ss += a0.x * a0.x + a0.y * a0.y + a0.z * a0.z + a0.w * a0.w +
              a1.x * a1.x + a1.y * a1.y + a1.z * a1.z + a1.w * a1.w;
        s16x8 av;
        av[0] = f2bf(a0.x); av[1] = f2bf(a0.y); av[2] = f2bf(a0.z); av[3] = f2bf(a0.w);
        av[4] = f2bf(a1.x); av[5] = f2bf(a1.y); av[6] = f2bf(a1.z); av[7] = f2bf(a1.w);
        s16x8 bv = *(const s16x8*)&brow[k0];
        *(s16x8*)&As[sm * 40 + kq] = av;
        *(s16x8*)&Bs[sm * 40 + kq] = bv;
        __syncthreads();
        s16x8 af[2], bf[4];
#pragma unroll
        for (int i = 0; i < 2; i++)
            af[i] = *(const s16x8*)&As[(mw + i * 16 + l15) * 40 + quad * 8];
#pragma unroll
        for (int j = 0; j < 4; j++)
            bf[j] = *(const s16x8*)&Bs[(nw + j * 16 + l15) * 40 + quad * 8];
#pragma unroll
        for (int i = 0; i < 2; i++)
#pragma unroll
            for (int j = 0; j < 4; j++)
                acc[i][j] = __builtin_amdgcn_mfma_f32_16x16x32_bf16(af[i], bf[j], acc[i][j], 0, 0, 0);
        // transpose-write raw-x tile to xbt[d][m] (256B contiguous segments)
        {
            s16x8 tv;
#pragma unroll
            for (int r = 0; r < 8; r++) tv[r] = As[(mg * 8 + r) * 40 + dl];
            *(s16x8*)&xbt[(size_t)(k0 + dl) * TOK + r0 + mg * 8] = tv;
        }
        __syncthreads();
    }
    // row inverse norms: 4 consecutive lanes share a row
    ss += __shfl_xor(ss, 1, 64);
    ss += __shfl_xor(ss, 2, 64);
    if ((t & 3) == 0) rnS[sm] = 1.0f / fmaxf(sqrtf(ss), 1e-12f);
    __syncthreads();

    int bb = r0 >> 13;
    float rv[2][4];
#pragma unroll
    for (int i = 0; i < 2; i++) {
        int ml = mw + i * 16 + quad * 4;
        rv[i][0] = rnS[ml]; rv[i][1] = rnS[ml + 1];
        rv[i][2] = rnS[ml + 2]; rv[i][3] = rnS[ml + 3];
    }
    short4 ebf[2][4];
#pragma unroll
    for (int j = 0; j < 4; j++) {
        int n = nw + j * 16 + l15;
        float cs = 0.f;
#pragma unroll
        for (int i = 0; i < 2; i++) {
            int mb = r0 + mw + i * 16 + quad * 4;
            f32x4 vv = acc[i][j];
            float e0 = __expf(vv[0] * rv[i][0]), e1 = __expf(vv[1] * rv[i][1]);
            float e2 = __expf(vv[2] * rv[i][2]), e3 = __expf(vv[3] * rv[i][3]);
            cs += e0 + e1 + e2 + e3;
            E[(size_t)(mb + 0) * N_ + n] = e0;
            E[(size_t)(mb + 1) * N_ + n] = e1;
            E[(size_t)(mb + 2) * N_ + n] = e2;
            E[(size_t)(mb + 3) * N_ + n] = e3;
            short4 eb = {f2bf(e0 * rv[i][0]), f2bf(e1 * rv[i][1]),
                         f2bf(e2 * rv[i][2]), f2bf(e3 * rv[i][3])};
            ebf[i][j] = eb;
        }
        cs += __shfl_xor(cs, 16, 64);
        cs += __shfl_xor(cs, 32, 64);
        if (lane < 16) atomicAdd(&colsum[bb * N_ + n], cs);
    }
    // ewt[n][r0..r0+127] = bf16(E*rn) via LDS transpose, two 64-row n-halves
    short* T = smem;  // 64 x 136 shorts
#pragma unroll
    for (int h = 0; h < 2; h++) {
        if ((wid & 1) == h) {
#pragma unroll
            for (int i = 0; i < 2; i++) {
                int mb = mw + i * 16 + quad * 4;  // local m 0..127
#pragma unroll
                for (int j = 0; j < 4; j++) {
                    int nl = j * 16 + l15;       // local n within half 0..63
                    *(short4*)&T[nl * 136 + mb] = ebf[i][j];
                }
            }
        }
        __syncthreads();
        {
            int nl = t >> 3, c = t & 7;
            s16x8 v0 = *(const s16x8*)&T[nl * 136 + c * 16];
            s16x8 v1 = *(const s16x8*)&T[nl * 136 + c * 16 + 8];
            size_t go = (size_t)(h * 64 + nl) * TOK + r0 + c * 16;
            *(s16x8*)&ewt[go] = v0;
            *(s16x8*)&ewt[go + 8] = v1;
        }
        __syncthreads();
    }
}

// ---------------------------------------------------------------------------
// K3: xs partials via bf16 MFMA. part[mc][b][n][d] = sum_m ewt[n][m]*xbt[d][m].
// ewt already folds rn; xbt is raw x. Grid 256 blocks (XCD-swizzled so the
// 4 dt-siblings sharing an ewt chunk land on one XCD's L2). K=512 m/block.
__global__ __launch_bounds__(256) void k_xs(const short* __restrict__ ewt,
                                            const short* __restrict__ xbt,
                                            float* __restrict__ part) {
    __shared__ short An[128 * 40];  // [n][k-chunk 0..31]
    __shared__ short Bd[128 * 40];  // [d][k-chunk 0..31]
    int t = threadIdx.x;
    int bid = blockIdx.x;
    int bi = (bid & 7) * 32 + (bid >> 3);  // 256 blocks, 8 XCDs, chunk=32
    int dt = bi & 3, mc = (bi >> 2) & 15, b = bi >> 6;
    int d0 = dt * 128;
    size_t mbase = (size_t)b * M_ + (size_t)mc * MLEN;
    int srow = t >> 1, shalf = (t & 1) * 16;
    const short* arow = &ewt[(size_t)srow * TOK + mbase + shalf];
    const short* brow = &xbt[(size_t)(d0 + srow) * TOK + mbase + shalf];
    int wid = t >> 6, lane = t & 63;
    int quad = lane >> 4, l15 = lane & 15;
    int nw = (wid >> 1) * 64, dw = (wid & 1) * 64;
    f32x4 acc[4][4] = {};

    for (int k0 = 0; k0 < MLEN; k0 += 32) {
        s16x8 a0 = *(const s16x8*)&arow[k0];
        s16x8 a1 = *(const s16x8*)&arow[k0 + 8];
        s16x8 b0 = *(const s16x8*)&brow[k0];
        s16x8 b1 = *(const s16x8*)&brow[k0 + 8];
        *(s16x8*)&An[srow * 40 + shalf] = a0;
        *(s16x8*)&An[srow * 40 + shalf + 8] = a1;
        *(s16x8*)&Bd[srow * 40 + shalf] = b0;
        *(s16x8*)&Bd[srow * 40 + shalf + 8] = b1;
        __syncthreads();
        s16x8 af[4], bf[4];
#pragma unroll
        for (int i = 0; i < 4; i++)
            af[i] = *(const s16x8*)&An[(nw + i * 16 + l15) * 40 + quad * 8];
#pragma unroll
        for (int j = 0; j < 4; j++)
            bf[j] = *(const s16x8*)&Bd[(dw + j * 16 + l15) * 40 + quad * 8];
#pragma unroll
        for (int i = 0; i < 4; i++)
#pragma unroll
            for (int j = 0; j < 4; j++)
                acc[i][j] = __builtin_amdgcn_mfma_f32_16x16x32_bf16(af[i], bf[j], acc[i][j], 0, 0, 0);
        __syncthreads();
    }
    size_t pbase = (((size_t)mc * B_ + b) * N_) * D_ + d0;
#pragma unroll
    for (int i = 0; i < 4; i++) {
        int nb = nw + i * 16 + quad * 4;
#pragma unroll
        for (int j = 0; j < 4; j++) {
            int d = dw + j * 16 + l15;
            f32x4 vv = acc[i][j];
            part[pbase + (size_t)(nb + 0) * D_ + d] = vv[0];
            part[pbase + (size_t)(nb + 1) * D_ + d] = vv[1];
            part[pbase + (size_t)(nb + 2) * D_ + d] = vv[2];
            part[pbase + (size_t)(nb + 3) * D_ + d] = vv[3];
        }
    }
}

// ---------------------------------------------------------------------------
// K3b: reduce partials over mc, normalize by colsum -> xs[b][n][d] fp32
__global__ __launch_bounds__(256) void k_xsum(const float* __restrict__ part,
                                              const float* __restrict__ colsum,
                                              float* __restrict__ xs) {
    int bi = blockIdx.x;  // b*N + n
    int tid = threadIdx.x;
    float inv = 1.0f / colsum[bi];
    size_t base = (size_t)bi * D_ + tid * 2;
    float sx = 0.f, sy = 0.f;
#pragma unroll 8
    for (int mc = 0; mc < MC_; mc++) {
        float2 v = *(const float2*)&part[(size_t)mc * (B_ * N_ * D_) + base];
        sx += v.x;
        sy += v.y;
    }
    float2 o = {sx * inv, sy * inv};
    *(float2*)&xs[base] = o;
}

// ---------------------------------------------------------------------------
// K4: per-expert linear (HBM-bound on W), bias add, fused bf16 transpose
// store ysT[b][e][n]. Grid n(128) x eq(4).
__global__ __launch_bounds__(256) void k_ys(const float* __restrict__ xs,
                                            const float* __restrict__ W,
                                            const float* __restrict__ bias,
                                            short* __restrict__ ysT) {
    __shared__ float xsn[B_][D_];
    int bi = blockIdx.x;
    int n = bi >> 2, eq = bi & 3;
    int tid = threadIdx.x;
    {
        int lb = tid >> 6, ld = (tid & 63) * 4;
        *(float4*)&xsn[lb][ld] = *(const float4*)&xs[((size_t)lb * N_ + n) * D_ + ld];
        *(float4*)&xsn[lb][256 + ld] =
            *(const float4*)&xs[((size_t)lb * N_ + n) * D_ + 256 + ld];
    }
    __syncthreads();
    int b = tid >> 6;
    int e = eq * 128 + (tid & 63) * 2;
    const float* Wn = W + (size_t)n * D_ * D_ + e;
    float a0 = 0.f, a1 = 0.f;
#pragma unroll 8
    for (int d = 0; d < D_; d++) {
        float2 w = *(const float2*)&Wn[(size_t)d * D_];
        float xv = xsn[b][d];
        a0 += xv * w.x;
        a1 += xv * w.y;
    }
    float2 bv = *(const float2*)&bias[n * D_ + e];
    ysT[((size_t)b * D_ + e) * N_ + n] = f2bf(a0 + bv.x);
    ysT[((size_t)b * D_ + e + 1) * N_ + n] = f2bf(a1 + bv.y);
}

// ---------------------------------------------------------------------------
// K5: combine via bf16 MFMA. Block: 128m x 128d, K=n=128 in 4 chunks of 32.
// XCD-swizzled so the 4 dt-siblings re-reading the same E rows share an L2.
__global__ __launch_bounds__(256) void k_combine(const float* __restrict__ E,
                                                 const short* __restrict__ ysT,
                                                 float* __restrict__ y) {
    __shared__ short As[128 * 40];  // [m][n-chunk 0..31]
    __shared__ short Bs[128 * 40];  // [d][n-chunk 0..31]
    __shared__ float rsA[2][128];
    __shared__ float rsinv[128];
    int t = threadIdx.x;
    int bid = blockIdx.x;
    int bi = (bid & 7) * 128 + (bid >> 3);  // 1024 blocks, 8 XCDs, chunk=128
    int dt = bi & 3, mt = bi >> 2;
    int r0 = mt * 128, d0 = dt * 128;
    int bb = r0 >> 13;
    int sm = t >> 1, nh = (t & 1) * 16;
    const float* erow = &E[(size_t)(r0 + sm) * N_ + nh];
    const short* yrow = &ysT[((size_t)bb * D_ + d0 + sm) * N_ + nh];
    int wid = t >> 6, lane = t & 63;
    int quad = lane >> 4, l15 = lane & 15;
    int mw = (wid >> 1) * 64, dw = (wid & 1) * 64;
    f32x4 acc[4][4] = {};
    float rsp = 0.f;

    for (int ks = 0; ks < 4; ks++) {
        int n0 = ks * 32;
        float4 e0 = *(const float4*)&erow[n0];
        float4 e1 = *(const float4*)&erow[n0 + 4];
        float4 e2 = *(const float4*)&erow[n0 + 8];
        float4 e3 = *(const float4*)&erow[n0 + 12];
        rsp += e0.x + e0.y + e0.z + e0.w + e1.x + e1.y + e1.z + e1.w +
               e2.x + e2.y + e2.z + e2.w + e3.x + e3.y + e3.z + e3.w;
        short4 w0 = {f2bf(e0.x), f2bf(e0.y), f2bf(e0.z), f2bf(e0.w)};
        short4 w1 = {f2bf(e1.x), f2bf(e1.y), f2bf(e1.z), f2bf(e1.w)};
        short4 w2 = {f2bf(e2.x), f2bf(e2.y), f2bf(e2.z), f2bf(e2.w)};
        short4 w3 = {f2bf(e3.x), f2bf(e3.y), f2bf(e3.z), f2bf(e3.w)};
        *(short4*)&As[sm * 40 + nh + 0] = w0;
        *(short4*)&As[sm * 40 + nh + 4] = w1;
        *(short4*)&As[sm * 40 + nh + 8] = w2;
        *(short4*)&As[sm * 40 + nh + 12] = w3;
        *(s16x8*)&Bs[sm * 40 + nh] = *(const s16x8*)&yrow[n0];
        *(s16x8*)&Bs[sm * 40 + nh + 8] = *(const s16x8*)&yrow[n0 + 8];
        __syncthreads();
        s16x8 af[4], bf[4];
#pragma unroll
        for (int i = 0; i < 4; i++)
            af[i] = *(const s16x8*)&As[(mw + i * 16 + l15) * 40 + quad * 8];
#pragma unroll
        for (int j = 0; j < 4; j++)
            bf[j] = *(const s16x8*)&Bs[(dw + j * 16 + l15) * 40 + quad * 8];
#pragma unroll
        for (int i = 0; i < 4; i++)
#pragma unroll
            for (int j = 0; j < 4; j++)
                acc[i][j] = __builtin_amdgcn_mfma_f32_16x16x32_bf16(af[i], bf[j], acc[i][j], 0, 0, 0);
        __syncthreads();
    }
    rsA[t & 1][sm] = rsp;
    __syncthreads();
    if (t < 128) rsinv[t] = 1.0f / (rsA[0][t] + rsA[1][t]);
    __syncthreads();
#pragma unroll
    for (int i = 0; i < 4; i++) {
        int mb = mw + i * 16 + quad * 4;
        float i0 = rsinv[mb], i1 = rsinv[mb + 1], i2 = rsinv[mb + 2], i3 = rsinv[mb + 3];
#pragma unroll
        for (int j = 0; j < 4; j++) {
            int d = d0 + dw + j * 16 + l15;
            f32x4 v = acc[i][j];
            y[(size_t)(r0 + mb + 0) * D_ + d] = v[0] * i0;
            y[(size_t)(r0 + mb + 1) * D_ + d] = v[1] * i1;
            y[(size_t)(r0 + mb + 2) * D_ + d] = v[2] * i2;
            y[(size_t)(r0 + mb + 3) * D_ + d] = v[3] * i3;
        }
    }
}

// ---------------------------------------------------------------------------
extern "C" void kernel_launch(void* const* d_in, const int* in_sizes, int n_in,
                              void* d_out, int out_size, void* d_ws, size_t ws_size,
                              hipStream_t stream) {
    const float* x = (const float*)d_in[0];
    const float* phi = (const float*)d_in[1];
    const float* scale = (const float*)d_in[2];
    const float* W = (const float*)d_in[3];
    const float* bias = (const float*)d_in[4];
    float* y = (float*)d_out;
    float* ws = (float*)d_ws;

    float* colsum = ws + OFF_CS;
    float* xs = ws + OFF_XS;
    short* pbt = (short*)(ws + OFF_PBT);
    float* E = ws + OFF_E;
    short* ewt = (short*)(ws + OFF_EWT);
    short* xbt = (short*)(ws + OFF_XBT);
    short* ysT = (short*)(ws + OFF_YST);
    float* part = ws + OFF_XP;

    hipMemsetAsync(colsum, 0, 512 * sizeof(float), stream);

    k_phinorm<<<N_, 128, 0, stream>>>(phi, scale, pbt);
    k_logits<<<TOK / 128, 512, 0, stream>>>(x, pbt, E, ewt, xbt, colsum);
    k_xs<<<B_ * MC_ * 4, 256, 0, stream>>>(ewt, xbt, part);
    k_xsum<<<B_ * N_, 256, 0, stream>>>(part, colsum, xs);
    k_ys<<<N_ * 4, 256, 0, stream>>>(xs, W, bias, ysT);
    k_combine<<<(TOK / 128) * 4, 256, 0, stream>>>(E, ysT, y);
}